// Round 6
// baseline (1188.764 us; speedup 1.0000x reference)
//
#include <hip/hip_runtime.h>
#include <hip/hip_bf16.h>
#include <hip/hip_fp16.h>

#define DIMD 256
#define SLEN 4096
#define KT 32

typedef __attribute__((ext_vector_type(8))) short short8;
typedef __attribute__((ext_vector_type(4))) short bf16x4;
typedef __attribute__((ext_vector_type(4))) float f32x4;
typedef unsigned int u32;

__device__ __forceinline__ ushort f2bf(float x) {
  union { float f; unsigned u; } v; v.f = x;
  unsigned r = v.u + 0x7fffu + ((v.u >> 16) & 1u);
  return (ushort)(r >> 16);
}

// async 16B global->LDS DMA; lds base wave-uniform, lanes fill base+lane*16
typedef __attribute__((address_space(1))) const u32 g_u32;
typedef __attribute__((address_space(3))) u32 l_u32;
__device__ __forceinline__ void gld_lds16(const void* g, void* l) {
  __builtin_amdgcn_global_load_lds((g_u32*)g, (l_u32*)l, 16, 0, 0);
}

// ---------------- W transpose + bf16: Wt[n][k] from W[k][n] ----------------
__global__ __launch_bounds__(256) void wt_prep(const float* __restrict__ W,
                                               ushort* __restrict__ Wt) {
  __shared__ float T[32][257];
  const int t = threadIdx.x;
  const int n0 = blockIdx.x * 32;
#pragma unroll
  for (int pass = 0; pass < 8; ++pass) {
    const int k = pass * 32 + (t >> 3);
    const int c4 = (t & 7) * 4;
    const float4 f = *(const float4*)&W[(size_t)k * 768 + n0 + c4];
    T[c4 + 0][k] = f.x; T[c4 + 1][k] = f.y; T[c4 + 2][k] = f.z; T[c4 + 3][k] = f.w;
  }
  __syncthreads();
  const int n = t >> 3, kb = (t & 7) * 32;
#pragma unroll
  for (int j8 = 0; j8 < 4; ++j8) {
    short8 o;
#pragma unroll
    for (int j = 0; j < 8; ++j) o[j] = (short)f2bf(T[n][kb + j8 * 8 + j]);
    *(short8*)&Wt[(size_t)(n0 + n) * 256 + kb + j8 * 8] = o;
  }
}

// ---------------- MFMA QKV projection: [16384,256] @ [256,768] + b ----------------
// blockIdx.y selects segment (0=Q scaled 1/16, 1=K, 2=V transposed+j-permuted).
__global__ __launch_bounds__(256, 2) void qkv_proj(const float* __restrict__ X,
                                                   const ushort* __restrict__ Wt,
                                                   const float* __restrict__ bias,
                                                   ushort* __restrict__ Qo,
                                                   ushort* __restrict__ Ko,
                                                   ushort* __restrict__ Vto) {
  __shared__ ushort Xs[128 * 36];   // 72B-padded rows -> conflict-free b128 frags
  __shared__ ushort Ws[256 * 36];
  const int tid = threadIdx.x;
  const int w = tid >> 6, lane = tid & 63;
  const int qa = lane & 15, hi = lane >> 4;
  const int m0 = blockIdx.x * 128;
  const int seg = blockIdx.y;
  const int n0 = seg * 256;

  f32x4 acc[2][16];
#pragma unroll
  for (int t = 0; t < 2; ++t)
#pragma unroll
    for (int dc = 0; dc < 16; ++dc) acc[t][dc] = (f32x4){0.f, 0.f, 0.f, 0.f};

  for (int k0 = 0; k0 < 256; k0 += 32) {
    __syncthreads();
#pragma unroll
    for (int pass = 0; pass < 4; ++pass) {   // X tile [128][32] fp32 -> bf16
      const int row = pass * 32 + (tid >> 3);
      const int c = tid & 7;
      const float4 f = *(const float4*)&X[(size_t)(m0 + row) * 256 + k0 + c * 4];
      bf16x4 h = {(short)f2bf(f.x), (short)f2bf(f.y), (short)f2bf(f.z), (short)f2bf(f.w)};
      *(bf16x4*)&Xs[row * 36 + c * 4] = h;
    }
#pragma unroll
    for (int pass = 0; pass < 4; ++pass) {   // Wt tile [256][32] bf16
      const int n = pass * 64 + (tid >> 2);
      const int c = (tid & 3) * 8;
      short8 v = *(const short8*)&Wt[(size_t)(n0 + n) * 256 + k0 + c];
      *(short8*)&Ws[n * 36 + c] = v;
    }
    __syncthreads();
    const short8 xf0 = *(const short8*)&Xs[(w * 32 + qa) * 36 + hi * 8];
    const short8 xf1 = *(const short8*)&Xs[(w * 32 + 16 + qa) * 36 + hi * 8];
    __builtin_amdgcn_s_setprio(1);
#pragma unroll
    for (int dc = 0; dc < 16; ++dc) {
      const short8 wf = *(const short8*)&Ws[(dc * 16 + qa) * 36 + hi * 8];
      acc[0][dc] = __builtin_amdgcn_mfma_f32_16x16x32_bf16(xf0, wf, acc[0][dc], 0, 0, 0);
      acc[1][dc] = __builtin_amdgcn_mfma_f32_16x16x32_bf16(xf1, wf, acc[1][dc], 0, 0, 0);
    }
    __builtin_amdgcn_s_setprio(0);
  }

  const float sc = (seg == 0) ? 0.0625f : 1.0f;
#pragma unroll
  for (int dc = 0; dc < 16; ++dc) {
    const int nn = dc * 16 + qa;
    const float bv = bias[n0 + nn];
#pragma unroll
    for (int t = 0; t < 2; ++t) {
#pragma unroll
      for (int r = 0; r < 4; ++r) {
        const int m = m0 + w * 32 + t * 16 + hi * 4 + r;
        const ushort h = f2bf((acc[t][dc][r] + bv) * sc);
        if (seg == 0)      Qo[(size_t)m * 256 + nn] = h;
        else if (seg == 1) Ko[(size_t)m * 256 + nn] = h;
        else {
          const int bi = m >> 12, s = m & 4095;
          const int sp = (s & ~31) | ((s & 3) | (((s >> 4) & 1) << 2) | (((s >> 2) & 3) << 3));
          Vto[((size_t)bi * 256 + nn) * 4096 + sp] = h;
        }
      }
    }
  }
}

// ---- stage one K[32][256] + Vt[256][32] tile via DMA (8 waves), src pre-swizzled ----
__device__ __forceinline__ void stage_kv(ushort* KsB, ushort* VsB,
                                         const ushort* Kb, const ushort* Vtb,
                                         int kv0, int w, int lane) {
#pragma unroll
  for (int it = 0; it < 2; ++it) {
    const int row = w * 4 + it * 2 + (lane >> 5);
    const int cb = (lane & 31) * 16;
    const char* src = (const char*)Kb + (size_t)(kv0 + row) * 512 + (cb ^ ((row & 7) << 4));
    gld_lds16(src, (char*)KsB + w * 2048 + it * 1024);
  }
#pragma unroll
  for (int it = 0; it < 2; ++it) {
    const int d = w * 32 + it * 16 + (lane >> 2);
    const int cb = (lane & 3) * 16;
    const char* src = (const char*)Vtb + (size_t)d * 8192 + (size_t)kv0 * 2 + (cb ^ ((d & 3) << 4));
    gld_lds16(src, (char*)VsB + w * 2048 + it * 1024);
  }
}

// ------- flash attention: 8 waves x 32 q-rows, dbuf DMA staging, reg softmax -------
__global__ __launch_bounds__(512, 4) void flash_attn(const ushort* __restrict__ Q,
                                                     const ushort* __restrict__ K,
                                                     const ushort* __restrict__ Vt,
                                                     float* __restrict__ Out,
                                                     __half* __restrict__ Op,
                                                     float* __restrict__ Mp,
                                                     int nsplit, int kvn) {
  __shared__ __attribute__((aligned(16))) ushort Ks[2][KT * DIMD];
  __shared__ __attribute__((aligned(16))) ushort Vs[2][DIMD * KT];

  const int tid = threadIdx.x;
  const int w = tid >> 6, lane = tid & 63;
  const int nwg = gridDim.x;                       // 64*nsplit, multiple of 8
  const int wg = (blockIdx.x & 7) * (nwg >> 3) + (blockIdx.x >> 3);
  const int split = wg >> 6;
  const int rest = wg & 63;
  const int b = rest >> 4;
  const int q0 = (rest & 15) * 256;
  const int qa = lane & 15, hi = lane >> 4;

  const ushort* Qr0 = Q + (size_t)(b * SLEN + q0 + w * 32 + qa) * DIMD;
  short8 qf0[8], qf1[8];
#pragma unroll
  for (int dc = 0; dc < 8; ++dc) {
    qf0[dc] = *(const short8*)(Qr0 + dc * 32 + hi * 8);
    qf1[dc] = *(const short8*)(Qr0 + 16 * DIMD + dc * 32 + hi * 8);
  }

  const f32x4 zero = {0.f, 0.f, 0.f, 0.f};
  f32x4 acc[2][16];
#pragma unroll
  for (int t = 0; t < 2; ++t)
#pragma unroll
    for (int dc = 0; dc < 16; ++dc) acc[t][dc] = zero;
  float mold0 = -1e30f, lrun0 = 0.f, mold1 = -1e30f, lrun1 = 0.f;  // q = qa per tile

  const ushort* Kb = K + (size_t)b * SLEN * DIMD;
  const ushort* Vtb = Vt + (size_t)b * DIMD * SLEN;
  const int kv_begin = split * kvn, kv_end = kv_begin + kvn;

  stage_kv(Ks[0], Vs[0], Kb, Vtb, kv_begin, w, lane);
  __syncthreads();
  int buf = 0;

  for (int kv0 = kv_begin; kv0 < kv_end; kv0 += KT) {
    if (kv0 + KT < kv_end)
      stage_kv(Ks[buf ^ 1], Vs[buf ^ 1], Kb, Vtb, kv0 + KT, w, lane);
    const char* KsB = (const char*)Ks[buf];
    const char* VsB = (const char*)Vs[buf];

    // ---- S^T = K Q^T : lane (qa,hi) holds S[k=hi*4+r(+16)][q=qa] per q-tile
    f32x4 sa0 = zero, sa1 = zero, sb0 = zero, sb1 = zero;
    __builtin_amdgcn_s_setprio(1);
#pragma unroll
    for (int dc = 0; dc < 8; ++dc) {
      const int cb = dc * 64 + hi * 16;
      const short8 kf0 = *(const short8*)(KsB + ((qa * 512 + cb) ^ ((qa & 7) << 4)));
      const short8 kf1 = *(const short8*)(KsB + (((qa + 16) * 512 + cb) ^ ((qa & 7) << 4)));
      sa0 = __builtin_amdgcn_mfma_f32_16x16x32_bf16(kf0, qf0[dc], sa0, 0, 0, 0);
      sa1 = __builtin_amdgcn_mfma_f32_16x16x32_bf16(kf1, qf0[dc], sa1, 0, 0, 0);
      sb0 = __builtin_amdgcn_mfma_f32_16x16x32_bf16(kf0, qf1[dc], sb0, 0, 0, 0);
      sb1 = __builtin_amdgcn_mfma_f32_16x16x32_bf16(kf1, qf1[dc], sb1, 0, 0, 0);
    }
    __builtin_amdgcn_s_setprio(0);

    // ---- in-register online softmax (per q-tile): 8 in-lane fmax + 2 shfl
    float m8a = fmaxf(fmaxf(fmaxf(sa0[0], sa0[1]), fmaxf(sa0[2], sa0[3])),
                      fmaxf(fmaxf(sa1[0], sa1[1]), fmaxf(sa1[2], sa1[3])));
    float m8b = fmaxf(fmaxf(fmaxf(sb0[0], sb0[1]), fmaxf(sb0[2], sb0[3])),
                      fmaxf(fmaxf(sb1[0], sb1[1]), fmaxf(sb1[2], sb1[3])));
    m8a = fmaxf(m8a, __shfl_xor(m8a, 16)); m8a = fmaxf(m8a, __shfl_xor(m8a, 32));
    m8b = fmaxf(m8b, __shfl_xor(m8b, 16)); m8b = fmaxf(m8b, __shfl_xor(m8b, 32));
    if (!__all(fmaxf(m8a - mold0, m8b - mold1) <= 4.0f)) {   // defer-max THR=4
      const float mn0 = fmaxf(mold0, m8a), fr0 = __expf(mold0 - mn0);
      const float mn1 = fmaxf(mold1, m8b), fr1 = __expf(mold1 - mn1);
      mold0 = mn0; lrun0 *= fr0; mold1 = mn1; lrun1 *= fr1;
      float fA[4], fB[4];
#pragma unroll
      for (int r = 0; r < 4; ++r) { fA[r] = __shfl(fr0, hi * 4 + r); fB[r] = __shfl(fr1, hi * 4 + r); }
#pragma unroll
      for (int dc = 0; dc < 16; ++dc)
#pragma unroll
        for (int r = 0; r < 4; ++r) { acc[0][dc][r] *= fA[r]; acc[1][dc][r] *= fB[r]; }
    }
    short8 af0, af1;
    float ls0 = 0.f, ls1 = 0.f;
#pragma unroll
    for (int r = 0; r < 4; ++r) {
      float p = __expf(sa0[r] - mold0); ls0 += p; af0[r] = (short)f2bf(p);
      p = __expf(sa1[r] - mold0); ls0 += p; af0[4 + r] = (short)f2bf(p);
      p = __expf(sb0[r] - mold1); ls1 += p; af1[r] = (short)f2bf(p);
      p = __expf(sb1[r] - mold1); ls1 += p; af1[4 + r] = (short)f2bf(p);
    }
    ls0 += __shfl_xor(ls0, 16); ls0 += __shfl_xor(ls0, 32); lrun0 += ls0;
    ls1 += __shfl_xor(ls1, 16); ls1 += __shfl_xor(ls1, 32); lrun1 += ls1;

    // ---- O += P @ V : single b128 B-frag (global j-permuted layout)
    __builtin_amdgcn_s_setprio(1);
#pragma unroll
    for (int dc = 0; dc < 16; ++dc) {
      const int d = dc * 16 + qa;
      const short8 vf = *(const short8*)(VsB + d * 64 + ((hi * 16) ^ ((d & 3) << 4)));
      acc[0][dc] = __builtin_amdgcn_mfma_f32_16x16x32_bf16(af0, vf, acc[0][dc], 0, 0, 0);
      acc[1][dc] = __builtin_amdgcn_mfma_f32_16x16x32_bf16(af1, vf, acc[1][dc], 0, 0, 0);
    }
    __builtin_amdgcn_s_setprio(0);
    __syncthreads();
    buf ^= 1;
  }

  // ---- epilogue: acc[t][dc][r] = O[q=t*16+hi*4+r][d=dc*16+qa] (unnormalized)
  float inv0[4], inv1[4];
#pragma unroll
  for (int r = 0; r < 4; ++r) {
    inv0[r] = 1.f / __shfl(lrun0, hi * 4 + r);
    inv1[r] = 1.f / __shfl(lrun1, hi * 4 + r);
  }
  if (nsplit == 1) {
    float* Ob = Out + (size_t)(b * SLEN + q0 + w * 32) * DIMD;
#pragma unroll
    for (int dc = 0; dc < 16; ++dc)
#pragma unroll
      for (int r = 0; r < 4; ++r) {
        Ob[(size_t)(hi * 4 + r) * DIMD + dc * 16 + qa] = acc[0][dc][r] * inv0[r];
        Ob[(size_t)(16 + hi * 4 + r) * DIMD + dc * 16 + qa] = acc[1][dc][r] * inv1[r];
      }
  } else {
    // normalized fp16 partials + per-split logsumexp
    const size_t qrow0 = (size_t)b * SLEN + q0 + w * 32;
#pragma unroll
    for (int dc = 0; dc < 16; ++dc)
#pragma unroll
      for (int r = 0; r < 4; ++r) {
        Op[((qrow0 + hi * 4 + r) * nsplit + split) * DIMD + dc * 16 + qa] =
            __float2half(acc[0][dc][r] * inv0[r]);
        Op[((qrow0 + 16 + hi * 4 + r) * nsplit + split) * DIMD + dc * 16 + qa] =
            __float2half(acc[1][dc][r] * inv1[r]);
      }
    if (hi == 0) {
      Mp[(qrow0 + qa) * nsplit + split] = mold0 + __logf(lrun0);
      Mp[(qrow0 + 16 + qa) * nsplit + split] = mold1 + __logf(lrun1);
    }
  }
}

// ------------- merge normalized partials across kv-splits -------------
__global__ __launch_bounds__(256) void attn_merge(const __half* __restrict__ Op,
                                                  const float* __restrict__ Mp,
                                                  float* __restrict__ Out, int nsplit) {
  const int q = blockIdx.x, d = threadIdx.x;
  float Mx = -1e30f;
  for (int i = 0; i < nsplit; ++i) Mx = fmaxf(Mx, Mp[(size_t)q * nsplit + i]);
  float Wsum = 0.f, o = 0.f;
  for (int i = 0; i < nsplit; ++i) {
    const float wgt = __expf(Mp[(size_t)q * nsplit + i] - Mx);
    Wsum += wgt;
    o += wgt * __half2float(Op[((size_t)q * nsplit + i) * DIMD + d]);
  }
  Out[(size_t)q * DIMD + d] = o / Wsum;
}

extern "C" void kernel_launch(void* const* d_in, const int* in_sizes, int n_in,
                              void* d_out, int out_size, void* d_ws, size_t ws_size,
                              hipStream_t stream) {
  const float* X = (const float*)d_in[0];
  const float* W = (const float*)d_in[1];
  const float* bias = (const float*)d_in[2];
  char* wsb = (char*)d_ws;
  ushort* qw = (ushort*)wsb;                       // 8 MB
  ushort* kw = qw + (size_t)16384 * 256;           // 8 MB
  ushort* vtw = kw + (size_t)16384 * 256;          // 8 MB (V^T, j-permuted)
  ushort* wt = vtw + (size_t)16384 * 256;          // 384 KB (W^T bf16)
  const size_t head_bytes = (size_t)3 * 16384 * 256 * 2 + 768 * 256 * 2;
  const size_t per_split = (size_t)16384 * 256 * 2 + (size_t)16384 * 4;  // fp16 O + fp32 M
  int nsplit = 1;
  if (ws_size >= head_bytes + 8 * per_split)      nsplit = 8;
  else if (ws_size >= head_bytes + 4 * per_split) nsplit = 4;
  else if (ws_size >= head_bytes + 2 * per_split) nsplit = 2;
  __half* Op = (__half*)(wsb + head_bytes);
  float* Mp = (float*)(wsb + head_bytes + (size_t)nsplit * 16384 * 256 * 2);

  wt_prep<<<dim3(24), 256, 0, stream>>>(W, wt);
  qkv_proj<<<dim3(128, 3), 256, 0, stream>>>(X, wt, bias, qw, kw, vtw);
  flash_attn<<<dim3(64 * nsplit), 512, 0, stream>>>(qw, kw, vtw, (float*)d_out,
                                                    Op, Mp, nsplit, 4096 / nsplit);
  if (nsplit > 1)
    attn_merge<<<dim3(16384), 256, 0, stream>>>(Op, Mp, (float*)d_out, nsplit);
}

// Round 7
// 180.795 us; speedup vs baseline: 6.5752x; 6.5752x over previous
//
#include <hip/hip_runtime.h>
#include <hip/hip_bf16.h>
#include <hip/hip_fp16.h>

#define DIMD 256
#define SLEN 4096
#define KT 32

typedef __attribute__((ext_vector_type(8))) short short8;
typedef __attribute__((ext_vector_type(4))) short bf16x4;
typedef __attribute__((ext_vector_type(4))) float f32x4;
typedef __attribute__((ext_vector_type(16))) float f32x16;
typedef unsigned int u32;

union frag_u { u32 u[4]; short8 v; };

__device__ __forceinline__ ushort f2bf(float x) {
  union { float f; unsigned u; } v; v.f = x;
  unsigned r = v.u + 0x7fffu + ((v.u >> 16) & 1u);
  return (ushort)(r >> 16);
}
__device__ __forceinline__ u32 packbf(float a, float b) {
  union { float f; u32 u; } x, y; x.f = a; y.f = b;
  const u32 lo = (x.u + 0x7fffu + ((x.u >> 16) & 1u)) >> 16;
  const u32 hi = (y.u + 0x7fffu + ((y.u >> 16) & 1u)) & 0xffff0000u;
  return lo | hi;
}

// async 16B global->LDS DMA; lds base wave-uniform, lanes fill base+lane*16
typedef __attribute__((address_space(1))) const u32 g_u32;
typedef __attribute__((address_space(3))) u32 l_u32;
__device__ __forceinline__ void gld_lds16(const void* g, void* l) {
  __builtin_amdgcn_global_load_lds((g_u32*)g, (l_u32*)l, 16, 0, 0);
}

// ---------------- W transpose + bf16: Wt[n][k] from W[k][n] ----------------
__global__ __launch_bounds__(256) void wt_prep(const float* __restrict__ W,
                                               ushort* __restrict__ Wt) {
  __shared__ float T[32][257];
  const int t = threadIdx.x;
  const int n0 = blockIdx.x * 32;
#pragma unroll
  for (int pass = 0; pass < 8; ++pass) {
    const int k = pass * 32 + (t >> 3);
    const int c4 = (t & 7) * 4;
    const float4 f = *(const float4*)&W[(size_t)k * 768 + n0 + c4];
    T[c4 + 0][k] = f.x; T[c4 + 1][k] = f.y; T[c4 + 2][k] = f.z; T[c4 + 3][k] = f.w;
  }
  __syncthreads();
  const int n = t >> 3, kb = (t & 7) * 32;
#pragma unroll
  for (int j8 = 0; j8 < 4; ++j8) {
    short8 o;
#pragma unroll
    for (int j = 0; j < 8; ++j) o[j] = (short)f2bf(T[n][kb + j8 * 8 + j]);
    *(short8*)&Wt[(size_t)(n0 + n) * 256 + kb + j8 * 8] = o;
  }
}

// ---------------- MFMA QKV projection: [16384,256] @ [256,768] + b ----------------
// blockIdx.y selects segment (0=Q scaled 1/16, 1=K, 2=V transposed, natural s).
__global__ __launch_bounds__(256, 2) void qkv_proj(const float* __restrict__ X,
                                                   const ushort* __restrict__ Wt,
                                                   const float* __restrict__ bias,
                                                   ushort* __restrict__ Qo,
                                                   ushort* __restrict__ Ko,
                                                   ushort* __restrict__ Vto) {
  __shared__ ushort Xs[128 * 36];   // 72B-padded rows -> conflict-free b128 frags
  __shared__ ushort Ws[256 * 36];
  const int tid = threadIdx.x;
  const int w = tid >> 6, lane = tid & 63;
  const int qa = lane & 15, hi = lane >> 4;
  const int m0 = blockIdx.x * 128;
  const int seg = blockIdx.y;
  const int n0 = seg * 256;

  f32x4 acc[2][16];
#pragma unroll
  for (int t = 0; t < 2; ++t)
#pragma unroll
    for (int dc = 0; dc < 16; ++dc) acc[t][dc] = (f32x4){0.f, 0.f, 0.f, 0.f};

  for (int k0 = 0; k0 < 256; k0 += 32) {
    __syncthreads();
#pragma unroll
    for (int pass = 0; pass < 4; ++pass) {   // X tile [128][32] fp32 -> bf16
      const int row = pass * 32 + (tid >> 3);
      const int c = tid & 7;
      const float4 f = *(const float4*)&X[(size_t)(m0 + row) * 256 + k0 + c * 4];
      bf16x4 h = {(short)f2bf(f.x), (short)f2bf(f.y), (short)f2bf(f.z), (short)f2bf(f.w)};
      *(bf16x4*)&Xs[row * 36 + c * 4] = h;
    }
#pragma unroll
    for (int pass = 0; pass < 4; ++pass) {   // Wt tile [256][32] bf16
      const int n = pass * 64 + (tid >> 2);
      const int c = (tid & 3) * 8;
      short8 v = *(const short8*)&Wt[(size_t)(n0 + n) * 256 + k0 + c];
      *(short8*)&Ws[n * 36 + c] = v;
    }
    __syncthreads();
    const short8 xf0 = *(const short8*)&Xs[(w * 32 + qa) * 36 + hi * 8];
    const short8 xf1 = *(const short8*)&Xs[(w * 32 + 16 + qa) * 36 + hi * 8];
    __builtin_amdgcn_s_setprio(1);
#pragma unroll
    for (int dc = 0; dc < 16; ++dc) {
      const short8 wf = *(const short8*)&Ws[(dc * 16 + qa) * 36 + hi * 8];
      acc[0][dc] = __builtin_amdgcn_mfma_f32_16x16x32_bf16(xf0, wf, acc[0][dc], 0, 0, 0);
      acc[1][dc] = __builtin_amdgcn_mfma_f32_16x16x32_bf16(xf1, wf, acc[1][dc], 0, 0, 0);
    }
    __builtin_amdgcn_s_setprio(0);
  }

  const float sc = (seg == 0) ? 0.0625f : 1.0f;
#pragma unroll
  for (int dc = 0; dc < 16; ++dc) {
    const int nn = dc * 16 + qa;
    const float bv = bias[n0 + nn];
#pragma unroll
    for (int t = 0; t < 2; ++t) {
#pragma unroll
      for (int r = 0; r < 4; ++r) {
        const int m = m0 + w * 32 + t * 16 + hi * 4 + r;
        const ushort h = f2bf((acc[t][dc][r] + bv) * sc);
        if (seg == 0)      Qo[(size_t)m * 256 + nn] = h;
        else if (seg == 1) Ko[(size_t)m * 256 + nn] = h;
        else {
          const int bi = m >> 12, s = m & 4095;
          Vto[((size_t)bi * 256 + nn) * 4096 + s] = h;
        }
      }
    }
  }
}

// ---- stage one K[32][256] + Vt[256][32] tile via DMA (4 waves), src pre-swizzled ----
__device__ __forceinline__ void stage_kv(ushort* KsB, ushort* VsB,
                                         const ushort* Kb, const ushort* Vtb,
                                         int kv0, int w, int lane) {
#pragma unroll
  for (int it = 0; it < 4; ++it) {
    const int row = w * 8 + it * 2 + (lane >> 5);
    const int cb = (lane & 31) * 16;
    const char* src = (const char*)Kb + (size_t)(kv0 + row) * 512 + (cb ^ ((row & 7) << 4));
    gld_lds16(src, (char*)KsB + w * 4096 + it * 1024);
  }
#pragma unroll
  for (int it = 0; it < 4; ++it) {
    const int d = w * 64 + it * 16 + (lane >> 2);
    const int cb = (lane & 3) * 16;
    const char* src = (const char*)Vtb + (size_t)d * 8192 + (size_t)kv0 * 2 + (cb ^ ((d & 3) << 4));
    gld_lds16(src, (char*)VsB + w * 4096 + it * 1024);
  }
}

// ------- flash attention: 4 waves x 32 q-rows, 32x32x16 MFMA, reg softmax -------
__global__ __launch_bounds__(256, 2) void flash_attn(const ushort* __restrict__ Q,
                                                     const ushort* __restrict__ K,
                                                     const ushort* __restrict__ Vt,
                                                     float* __restrict__ Out,
                                                     __half* __restrict__ Op,
                                                     float* __restrict__ Mp,
                                                     int nsplit, int kvn) {
  __shared__ __attribute__((aligned(16))) ushort Ks[2][KT * DIMD];
  __shared__ __attribute__((aligned(16))) ushort Vs[2][DIMD * KT];

  const int tid = threadIdx.x;
  const int w = tid >> 6, lane = tid & 63;
  const int c = lane & 31, h = lane >> 5;
  const int nwg = gridDim.x;                       // 128*nsplit, multiple of 8
  const int wg = (blockIdx.x & 7) * (nwg >> 3) + (blockIdx.x >> 3);
  const int split = wg >> 7;
  const int rest = wg & 127;
  const int b = rest >> 5;
  const int q0 = (rest & 31) * 128;

  // Q B-frags: col=lane&31=q, k=h*8+j = d-within-chunk (Q pre-scaled by 1/16)
  const ushort* Qr = Q + (size_t)(b * SLEN + q0 + w * 32 + c) * DIMD;
  short8 qf[16];
#pragma unroll
  for (int dch = 0; dch < 16; ++dch)
    qf[dch] = *(const short8*)(Qr + dch * 16 + h * 8);

  f32x16 acc[8];
#pragma unroll
  for (int dc = 0; dc < 8; ++dc)
#pragma unroll
    for (int i = 0; i < 16; ++i) acc[dc][i] = 0.f;
  float mold = -1e30f, lrun = 0.f;   // per-lane, q = c (half-sums for l)

  const ushort* Kb = K + (size_t)b * SLEN * DIMD;
  const ushort* Vtb = Vt + (size_t)b * DIMD * SLEN;
  const int kv_begin = split * kvn, kv_end = kv_begin + kvn;

  stage_kv(Ks[0], Vs[0], Kb, Vtb, kv_begin, w, lane);
  __syncthreads();
  int buf = 0;

  for (int kv0 = kv_begin; kv0 < kv_end; kv0 += KT) {
    if (kv0 + KT < kv_end)
      stage_kv(Ks[buf ^ 1], Vs[buf ^ 1], Kb, Vtb, kv0 + KT, w, lane);
    const char* KsB = (const char*)Ks[buf];
    const char* VsB = (const char*)Vs[buf];

    // ---- S^T = K Q^T : C[row=kv (reg pattern), col=q=c]; 2 interleaved chains
    f32x16 s_a, s_b;
#pragma unroll
    for (int i = 0; i < 16; ++i) { s_a[i] = 0.f; s_b[i] = 0.f; }
    __builtin_amdgcn_s_setprio(1);
#pragma unroll
    for (int dch = 0; dch < 16; dch += 2) {
      const short8 kf0 = *(const short8*)(KsB + ((c * 512 + dch * 32 + h * 16) ^ ((c & 7) << 4)));
      const short8 kf1 = *(const short8*)(KsB + ((c * 512 + (dch + 1) * 32 + h * 16) ^ ((c & 7) << 4)));
      s_a = __builtin_amdgcn_mfma_f32_32x32x16_bf16(kf0, qf[dch], s_a, 0, 0, 0);
      s_b = __builtin_amdgcn_mfma_f32_32x32x16_bf16(kf1, qf[dch + 1], s_b, 0, 0, 0);
    }
    __builtin_amdgcn_s_setprio(0);
    float s[16];
#pragma unroll
    for (int i = 0; i < 16; ++i) s[i] = s_a[i] + s_b[i];

    // ---- softmax for q=c: 15 in-lane fmax + 1 shfl; l-sum deferred in-lane
    float m16 = s[0];
#pragma unroll
    for (int i = 1; i < 16; ++i) m16 = fmaxf(m16, s[i]);
    m16 = fmaxf(m16, __shfl_xor(m16, 32));
    if (!__all(m16 - mold <= 4.0f)) {      // defer-max THR=4 (rare)
      const float mnew = fmaxf(mold, m16);
      const float fr = __expf(mold - mnew);
      mold = mnew;
      lrun *= fr;
#pragma unroll
      for (int r = 0; r < 16; ++r) {
        const float frr = __shfl(fr, (r & 3) + 8 * (r >> 2) + 4 * h);
#pragma unroll
        for (int dc = 0; dc < 8; ++dc) acc[dc][r] *= frr;
      }
    }
    float p[16];
#pragma unroll
    for (int r = 0; r < 16; ++r) {
      p[r] = __expf(s[r] - mold);
      lrun += p[r];
    }

    // ---- pack P -> bf16 u32 pairs; redistribute halves via shfl_xor(32)
    u32 wv[8];
#pragma unroll
    for (int i = 0; i < 8; ++i) wv[i] = packbf(p[2 * i], p[2 * i + 1]);
    const u32 x0 = __shfl_xor(h ? wv[0] : wv[2], 32);
    const u32 x1 = __shfl_xor(h ? wv[1] : wv[3], 32);
    const u32 x2 = __shfl_xor(h ? wv[4] : wv[6], 32);
    const u32 x3 = __shfl_xor(h ? wv[5] : wv[7], 32);
    frag_u a0, a1;   // A-frag row=q? no: A rows = P's 32 q? A = P[32q][16kv]: row=lane&31=q, k=h*8+j=kv
    a0.u[0] = h ? x0 : wv[0]; a0.u[1] = h ? x1 : wv[1];
    a0.u[2] = h ? wv[2] : x0; a0.u[3] = h ? wv[3] : x1;
    a1.u[0] = h ? x2 : wv[4]; a1.u[1] = h ? x3 : wv[5];
    a1.u[2] = h ? wv[6] : x2; a1.u[3] = h ? wv[7] : x3;

    // ---- O += P @ V : B = V[16kv][32d] single b128 per frag
    __builtin_amdgcn_s_setprio(1);
#pragma unroll
    for (int dc = 0; dc < 8; ++dc) {
      const int d = dc * 32 + c;
      const char* vrow = VsB + d * 64;
      const int sw = (d & 3) << 4;
      const short8 vf0 = *(const short8*)(vrow + ((h * 16) ^ sw));
      const short8 vf1 = *(const short8*)(vrow + ((32 + h * 16) ^ sw));
      acc[dc] = __builtin_amdgcn_mfma_f32_32x32x16_bf16(a0.v, vf0, acc[dc], 0, 0, 0);
      acc[dc] = __builtin_amdgcn_mfma_f32_32x32x16_bf16(a1.v, vf1, acc[dc], 0, 0, 0);
    }
    __builtin_amdgcn_s_setprio(0);
    __syncthreads();
    buf ^= 1;
  }

  // ---- epilogue: acc[dc][r] = O[q=(r&3)+8*(r>>2)+4h][d=dc*32+c] (unnormalized)
  lrun += __shfl_xor(lrun, 32);    // complete l[q=c] across halves
  if (nsplit == 1) {
    float* Ob = Out + (size_t)(b * SLEN + q0 + w * 32) * DIMD;
#pragma unroll
    for (int r = 0; r < 16; ++r) {
      const int q = (r & 3) + 8 * (r >> 2) + 4 * h;
      const float inv = 1.f / __shfl(lrun, q);
#pragma unroll
      for (int dc = 0; dc < 8; ++dc)
        Ob[(size_t)q * DIMD + dc * 32 + c] = acc[dc][r] * inv;
    }
  } else {
    const size_t qrow0 = (size_t)b * SLEN + q0 + w * 32;
#pragma unroll
    for (int r = 0; r < 16; ++r) {
      const int q = (r & 3) + 8 * (r >> 2) + 4 * h;
      const float inv = 1.f / __shfl(lrun, q);
#pragma unroll
      for (int dc = 0; dc < 8; ++dc)
        Op[((qrow0 + q) * nsplit + split) * DIMD + dc * 32 + c] =
            __float2half(acc[dc][r] * inv);
    }
    if (h == 0)
      Mp[(qrow0 + c) * nsplit + split] = mold + __logf(lrun);
  }
}

// ------------- merge normalized partials across kv-splits -------------
__global__ __launch_bounds__(256) void attn_merge(const __half* __restrict__ Op,
                                                  const float* __restrict__ Mp,
                                                  float* __restrict__ Out, int nsplit) {
  const int q = blockIdx.x, d = threadIdx.x;
  float Mx = -1e30f;
  for (int i = 0; i < nsplit; ++i) Mx = fmaxf(Mx, Mp[(size_t)q * nsplit + i]);
  float Wsum = 0.f, o = 0.f;
  for (int i = 0; i < nsplit; ++i) {
    const float wgt = __expf(Mp[(size_t)q * nsplit + i] - Mx);
    Wsum += wgt;
    o += wgt * __half2float(Op[((size_t)q * nsplit + i) * DIMD + d]);
  }
  Out[(size_t)q * DIMD + d] = o / Wsum;
}

extern "C" void kernel_launch(void* const* d_in, const int* in_sizes, int n_in,
                              void* d_out, int out_size, void* d_ws, size_t ws_size,
                              hipStream_t stream) {
  const float* X = (const float*)d_in[0];
  const float* W = (const float*)d_in[1];
  const float* bias = (const float*)d_in[2];
  char* wsb = (char*)d_ws;
  ushort* qw = (ushort*)wsb;                       // 8 MB
  ushort* kw = qw + (size_t)16384 * 256;           // 8 MB
  ushort* vtw = kw + (size_t)16384 * 256;          // 8 MB (V^T, natural s)
  ushort* wt = vtw + (size_t)16384 * 256;          // 384 KB (W^T bf16)
  const size_t head_bytes = (size_t)3 * 16384 * 256 * 2 + 768 * 256 * 2;
  const size_t per_split = (size_t)16384 * 256 * 2 + (size_t)16384 * 4;  // fp16 O + fp32 M
  int nsplit = 1;
  if (ws_size >= head_bytes + 4 * per_split)      nsplit = 4;
  else if (ws_size >= head_bytes + 2 * per_split) nsplit = 2;
  __half* Op = (__half*)(wsb + head_bytes);
  float* Mp = (float*)(wsb + head_bytes + (size_t)nsplit * 16384 * 256 * 2);

  wt_prep<<<dim3(24), 256, 0, stream>>>(W, wt);
  qkv_proj<<<dim3(128, 3), 256, 0, stream>>>(X, wt, bias, qw, kw, vtw);
  flash_attn<<<dim3(128 * nsplit), 256, 0, stream>>>(qw, kw, vtw, (float*)d_out,
                                                     Op, Mp, nsplit, 4096 / nsplit);
  if (nsplit > 1)
    attn_merge<<<dim3(16384), 256, 0, stream>>>(Op, Mp, (float*)d_out, nsplit);
}

// Round 8
// 156.582 us; speedup vs baseline: 7.5920x; 1.1546x over previous
//
#include <hip/hip_runtime.h>
#include <hip/hip_bf16.h>
#include <hip/hip_fp16.h>

#define DIMD 256
#define SLEN 4096
#define KT 32

typedef __attribute__((ext_vector_type(8))) short short8;
typedef __attribute__((ext_vector_type(4))) short bf16x4;
typedef __attribute__((ext_vector_type(4))) float f32x4;
typedef unsigned int u32;

__device__ __forceinline__ ushort f2bf(float x) {
  union { float f; unsigned u; } v; v.f = x;
  unsigned r = v.u + 0x7fffu + ((v.u >> 16) & 1u);
  return (ushort)(r >> 16);
}

// async 16B global->LDS DMA; lds base wave-uniform, lanes fill base+lane*16
typedef __attribute__((address_space(1))) const u32 g_u32;
typedef __attribute__((address_space(3))) u32 l_u32;
__device__ __forceinline__ void gld_lds16(const void* g, void* l) {
  __builtin_amdgcn_global_load_lds((g_u32*)g, (l_u32*)l, 16, 0, 0);
}

// ---------------- W transpose + bf16: Wt[n][k] from W[k][n] ----------------
__global__ __launch_bounds__(256) void wt_prep(const float* __restrict__ W,
                                               ushort* __restrict__ Wt) {
  __shared__ float T[32][257];
  const int t = threadIdx.x;
  const int n0 = blockIdx.x * 32;
#pragma unroll
  for (int pass = 0; pass < 8; ++pass) {
    const int k = pass * 32 + (t >> 3);
    const int c4 = (t & 7) * 4;
    const float4 f = *(const float4*)&W[(size_t)k * 768 + n0 + c4];
    T[c4 + 0][k] = f.x; T[c4 + 1][k] = f.y; T[c4 + 2][k] = f.z; T[c4 + 3][k] = f.w;
  }
  __syncthreads();
  const int n = t >> 3, kb = (t & 7) * 32;
#pragma unroll
  for (int j8 = 0; j8 < 4; ++j8) {
    short8 o;
#pragma unroll
    for (int j = 0; j < 8; ++j) o[j] = (short)f2bf(T[n][kb + j8 * 8 + j]);
    *(short8*)&Wt[(size_t)(n0 + n) * 256 + kb + j8 * 8] = o;
  }
}

// ---------------- MFMA QKV projection: [16384,256] @ [256,768] + b ----------------
// blockIdx.y selects segment (0=Q scaled 1/16, 1=K, 2=V transposed+j-permuted).
__global__ __launch_bounds__(256, 2) void qkv_proj(const float* __restrict__ X,
                                                   const ushort* __restrict__ Wt,
                                                   const float* __restrict__ bias,
                                                   ushort* __restrict__ Qo,
                                                   ushort* __restrict__ Ko,
                                                   ushort* __restrict__ Vto) {
  __shared__ ushort Xs[128 * 36];   // 72B-padded rows -> conflict-free b128 frags
  __shared__ ushort Ws[256 * 36];
  const int tid = threadIdx.x;
  const int w = tid >> 6, lane = tid & 63;
  const int qa = lane & 15, hi = lane >> 4;
  const int m0 = blockIdx.x * 128;
  const int seg = blockIdx.y;
  const int n0 = seg * 256;

  f32x4 acc[2][16];
#pragma unroll
  for (int t = 0; t < 2; ++t)
#pragma unroll
    for (int dc = 0; dc < 16; ++dc) acc[t][dc] = (f32x4){0.f, 0.f, 0.f, 0.f};

  for (int k0 = 0; k0 < 256; k0 += 32) {
    __syncthreads();
#pragma unroll
    for (int pass = 0; pass < 4; ++pass) {   // X tile [128][32] fp32 -> bf16
      const int row = pass * 32 + (tid >> 3);
      const int c = tid & 7;
      const float4 f = *(const float4*)&X[(size_t)(m0 + row) * 256 + k0 + c * 4];
      bf16x4 h = {(short)f2bf(f.x), (short)f2bf(f.y), (short)f2bf(f.z), (short)f2bf(f.w)};
      *(bf16x4*)&Xs[row * 36 + c * 4] = h;
    }
#pragma unroll
    for (int pass = 0; pass < 4; ++pass) {   // Wt tile [256][32] bf16
      const int n = pass * 64 + (tid >> 2);
      const int c = (tid & 3) * 8;
      short8 v = *(const short8*)&Wt[(size_t)(n0 + n) * 256 + k0 + c];
      *(short8*)&Ws[n * 36 + c] = v;
    }
    __syncthreads();
    const short8 xf0 = *(const short8*)&Xs[(w * 32 + qa) * 36 + hi * 8];
    const short8 xf1 = *(const short8*)&Xs[(w * 32 + 16 + qa) * 36 + hi * 8];
    __builtin_amdgcn_s_setprio(1);
#pragma unroll
    for (int dc = 0; dc < 16; ++dc) {
      const short8 wf = *(const short8*)&Ws[(dc * 16 + qa) * 36 + hi * 8];
      acc[0][dc] = __builtin_amdgcn_mfma_f32_16x16x32_bf16(xf0, wf, acc[0][dc], 0, 0, 0);
      acc[1][dc] = __builtin_amdgcn_mfma_f32_16x16x32_bf16(xf1, wf, acc[1][dc], 0, 0, 0);
    }
    __builtin_amdgcn_s_setprio(0);
  }

  const float sc = (seg == 0) ? 0.0625f : 1.0f;
#pragma unroll
  for (int dc = 0; dc < 16; ++dc) {
    const int nn = dc * 16 + qa;
    const float bv = bias[n0 + nn];
#pragma unroll
    for (int t = 0; t < 2; ++t) {
#pragma unroll
      for (int r = 0; r < 4; ++r) {
        const int m = m0 + w * 32 + t * 16 + hi * 4 + r;
        const ushort h = f2bf((acc[t][dc][r] + bv) * sc);
        if (seg == 0)      Qo[(size_t)m * 256 + nn] = h;
        else if (seg == 1) Ko[(size_t)m * 256 + nn] = h;
        else {
          const int bi = m >> 12, s = m & 4095;
          const int sp = (s & ~31) | ((s & 3) | (((s >> 4) & 1) << 2) | (((s >> 2) & 3) << 3));
          Vto[((size_t)bi * 256 + nn) * 4096 + sp] = h;
        }
      }
    }
  }
}

// ---- stage one K[32][256] + Vt[256][32] tile via DMA (8 waves), src pre-swizzled ----
__device__ __forceinline__ void stage_kv(ushort* KsB, ushort* VsB,
                                         const ushort* Kb, const ushort* Vtb,
                                         int kv0, int w, int lane) {
#pragma unroll
  for (int it = 0; it < 2; ++it) {
    const int row = w * 4 + it * 2 + (lane >> 5);
    const int cb = (lane & 31) * 16;
    const char* src = (const char*)Kb + (size_t)(kv0 + row) * 512 + (cb ^ ((row & 7) << 4));
    gld_lds16(src, (char*)KsB + w * 2048 + it * 1024);
  }
#pragma unroll
  for (int it = 0; it < 2; ++it) {
    const int d = w * 32 + it * 16 + (lane >> 2);
    const int cb = (lane & 3) * 16;
    const char* src = (const char*)Vtb + (size_t)d * 8192 + (size_t)kv0 * 2 + (cb ^ ((d & 3) << 4));
    gld_lds16(src, (char*)VsB + w * 2048 + it * 1024);
  }
}

// --- flash attention: 8 waves x 32 q-rows, 3-buf counted-vmcnt pipeline, 16x16 core ---
__global__ __launch_bounds__(512, 2) void flash_attn(const ushort* __restrict__ Q,
                                                     const ushort* __restrict__ K,
                                                     const ushort* __restrict__ Vt,
                                                     float* __restrict__ Out,
                                                     __half* __restrict__ Op,
                                                     float* __restrict__ Mp,
                                                     int nsplit, int kvn) {
  __shared__ __attribute__((aligned(16))) ushort Ks[3][KT * DIMD];   // 48 KB
  __shared__ __attribute__((aligned(16))) ushort Vs[3][DIMD * KT];   // 48 KB

  const int tid = threadIdx.x;
  const int w = tid >> 6, lane = tid & 63;
  const int nwg = gridDim.x;                       // 64*nsplit, multiple of 8
  const int wg = (blockIdx.x & 7) * (nwg >> 3) + (blockIdx.x >> 3);
  const int split = wg >> 6;
  const int rest = wg & 63;
  const int b = rest >> 4;
  const int q0 = (rest & 15) * 256;
  const int qa = lane & 15, hi = lane >> 4;

  const ushort* Qr0 = Q + (size_t)(b * SLEN + q0 + w * 32 + qa) * DIMD;
  short8 qf0[8], qf1[8];
#pragma unroll
  for (int dc = 0; dc < 8; ++dc) {
    qf0[dc] = *(const short8*)(Qr0 + dc * 32 + hi * 8);
    qf1[dc] = *(const short8*)(Qr0 + 16 * DIMD + dc * 32 + hi * 8);
  }

  const f32x4 zero = {0.f, 0.f, 0.f, 0.f};
  f32x4 acc[2][16];
#pragma unroll
  for (int t = 0; t < 2; ++t)
#pragma unroll
    for (int dc = 0; dc < 16; ++dc) acc[t][dc] = zero;
  float mold0 = -1e30f, lrun0 = 0.f, mold1 = -1e30f, lrun1 = 0.f;  // q = qa per tile

  const ushort* Kb = K + (size_t)b * SLEN * DIMD;
  const ushort* Vtb = Vt + (size_t)b * DIMD * SLEN;
  const int kv_begin = split * kvn;
  const int nt = kvn / KT;   // >= 32

  // prologue: 2 tiles in flight, wait for tile 0 only
  stage_kv(Ks[0], Vs[0], Kb, Vtb, kv_begin, w, lane);
  stage_kv(Ks[1], Vs[1], Kb, Vtb, kv_begin + KT, w, lane);
  asm volatile("s_waitcnt vmcnt(4)" ::: "memory");
  __builtin_amdgcn_s_barrier();
  __builtin_amdgcn_sched_barrier(0);

  int cur = 0;
  for (int it = 0; it < nt; ++it) {
    const bool pf = (it + 2 < nt);
    if (pf) {
      const int nb = (cur == 0) ? 2 : cur - 1;     // (cur+2)%3, read at it-1, safe
      stage_kv(Ks[nb], Vs[nb], Kb, Vtb, kv_begin + (it + 2) * KT, w, lane);
    }
    const char* KsB = (const char*)Ks[cur];
    const char* VsB = (const char*)Vs[cur];

    // ---- S^T = K Q^T : lane (qa,hi) holds S[k=hi*4+r(+16)][q=qa] per q-tile
    f32x4 sa0 = zero, sa1 = zero, sb0 = zero, sb1 = zero;
    __builtin_amdgcn_s_setprio(1);
#pragma unroll
    for (int dc = 0; dc < 8; ++dc) {
      const int cb = dc * 64 + hi * 16;
      const short8 kf0 = *(const short8*)(KsB + ((qa * 512 + cb) ^ ((qa & 7) << 4)));
      const short8 kf1 = *(const short8*)(KsB + (((qa + 16) * 512 + cb) ^ ((qa & 7) << 4)));
      sa0 = __builtin_amdgcn_mfma_f32_16x16x32_bf16(kf0, qf0[dc], sa0, 0, 0, 0);
      sa1 = __builtin_amdgcn_mfma_f32_16x16x32_bf16(kf1, qf0[dc], sa1, 0, 0, 0);
      sb0 = __builtin_amdgcn_mfma_f32_16x16x32_bf16(kf0, qf1[dc], sb0, 0, 0, 0);
      sb1 = __builtin_amdgcn_mfma_f32_16x16x32_bf16(kf1, qf1[dc], sb1, 0, 0, 0);
    }
    __builtin_amdgcn_s_setprio(0);

    // ---- in-register online softmax (per q-tile): 8 in-lane fmax + 2 shfl
    float m8a = fmaxf(fmaxf(fmaxf(sa0[0], sa0[1]), fmaxf(sa0[2], sa0[3])),
                      fmaxf(fmaxf(sa1[0], sa1[1]), fmaxf(sa1[2], sa1[3])));
    float m8b = fmaxf(fmaxf(fmaxf(sb0[0], sb0[1]), fmaxf(sb0[2], sb0[3])),
                      fmaxf(fmaxf(sb1[0], sb1[1]), fmaxf(sb1[2], sb1[3])));
    m8a = fmaxf(m8a, __shfl_xor(m8a, 16)); m8a = fmaxf(m8a, __shfl_xor(m8a, 32));
    m8b = fmaxf(m8b, __shfl_xor(m8b, 16)); m8b = fmaxf(m8b, __shfl_xor(m8b, 32));
    if (!__all(fmaxf(m8a - mold0, m8b - mold1) <= 4.0f)) {   // defer-max THR=4
      const float mn0 = fmaxf(mold0, m8a), fr0 = __expf(mold0 - mn0);
      const float mn1 = fmaxf(mold1, m8b), fr1 = __expf(mold1 - mn1);
      mold0 = mn0; lrun0 *= fr0; mold1 = mn1; lrun1 *= fr1;
      float fA[4], fB[4];
#pragma unroll
      for (int r = 0; r < 4; ++r) { fA[r] = __shfl(fr0, hi * 4 + r); fB[r] = __shfl(fr1, hi * 4 + r); }
#pragma unroll
      for (int dc = 0; dc < 16; ++dc)
#pragma unroll
        for (int r = 0; r < 4; ++r) { acc[0][dc][r] *= fA[r]; acc[1][dc][r] *= fB[r]; }
    }
    short8 af0, af1;
    float ls0 = 0.f, ls1 = 0.f;
#pragma unroll
    for (int r = 0; r < 4; ++r) {
      float p = __expf(sa0[r] - mold0); ls0 += p; af0[r] = (short)f2bf(p);
      p = __expf(sa1[r] - mold0); ls0 += p; af0[4 + r] = (short)f2bf(p);
      p = __expf(sb0[r] - mold1); ls1 += p; af1[r] = (short)f2bf(p);
      p = __expf(sb1[r] - mold1); ls1 += p; af1[4 + r] = (short)f2bf(p);
    }
    ls0 += __shfl_xor(ls0, 16); ls0 += __shfl_xor(ls0, 32); lrun0 += ls0;
    ls1 += __shfl_xor(ls1, 16); ls1 += __shfl_xor(ls1, 32); lrun1 += ls1;

    // ---- O += P @ V : single b128 B-frag (global j-permuted layout)
    __builtin_amdgcn_s_setprio(1);
#pragma unroll
    for (int dc = 0; dc < 16; ++dc) {
      const int d = dc * 16 + qa;
      const short8 vf = *(const short8*)(VsB + d * 64 + ((hi * 16) ^ ((d & 3) << 4)));
      acc[0][dc] = __builtin_amdgcn_mfma_f32_16x16x32_bf16(af0, vf, acc[0][dc], 0, 0, 0);
      acc[1][dc] = __builtin_amdgcn_mfma_f32_16x16x32_bf16(af1, vf, acc[1][dc], 0, 0, 0);
    }
    __builtin_amdgcn_s_setprio(0);

    // ---- counted drain: own DMA(it+1) landed, DMA(it+2) stays in flight
    if (pf) { asm volatile("s_waitcnt vmcnt(4)" ::: "memory"); }
    else    { asm volatile("s_waitcnt vmcnt(0)" ::: "memory"); }
    __builtin_amdgcn_s_barrier();
    __builtin_amdgcn_sched_barrier(0);
    cur = (cur == 2) ? 0 : cur + 1;
  }

  // ---- epilogue: acc[t][dc][r] = O[q=t*16+hi*4+r][d=dc*16+qa] (unnormalized)
  float inv0[4], inv1[4];
#pragma unroll
  for (int r = 0; r < 4; ++r) {
    inv0[r] = 1.f / __shfl(lrun0, hi * 4 + r);
    inv1[r] = 1.f / __shfl(lrun1, hi * 4 + r);
  }
  if (nsplit == 1) {
    float* Ob = Out + (size_t)(b * SLEN + q0 + w * 32) * DIMD;
#pragma unroll
    for (int dc = 0; dc < 16; ++dc)
#pragma unroll
      for (int r = 0; r < 4; ++r) {
        Ob[(size_t)(hi * 4 + r) * DIMD + dc * 16 + qa] = acc[0][dc][r] * inv0[r];
        Ob[(size_t)(16 + hi * 4 + r) * DIMD + dc * 16 + qa] = acc[1][dc][r] * inv1[r];
      }
  } else {
    // normalized fp16 partials + per-split logsumexp
    const size_t qrow0 = (size_t)b * SLEN + q0 + w * 32;
#pragma unroll
    for (int dc = 0; dc < 16; ++dc)
#pragma unroll
      for (int r = 0; r < 4; ++r) {
        Op[((qrow0 + hi * 4 + r) * nsplit + split) * DIMD + dc * 16 + qa] =
            __float2half(acc[0][dc][r] * inv0[r]);
        Op[((qrow0 + 16 + hi * 4 + r) * nsplit + split) * DIMD + dc * 16 + qa] =
            __float2half(acc[1][dc][r] * inv1[r]);
      }
    if (hi == 0) {
      Mp[(qrow0 + qa) * nsplit + split] = mold0 + __logf(lrun0);
      Mp[(qrow0 + 16 + qa) * nsplit + split] = mold1 + __logf(lrun1);
    }
  }
}

// ------------- merge normalized partials across kv-splits -------------
__global__ __launch_bounds__(256) void attn_merge(const __half* __restrict__ Op,
                                                  const float* __restrict__ Mp,
                                                  float* __restrict__ Out, int nsplit) {
  const int q = blockIdx.x, d = threadIdx.x;
  float Mx = -1e30f;
  for (int i = 0; i < nsplit; ++i) Mx = fmaxf(Mx, Mp[(size_t)q * nsplit + i]);
  float Wsum = 0.f, o = 0.f;
  for (int i = 0; i < nsplit; ++i) {
    const float wgt = __expf(Mp[(size_t)q * nsplit + i] - Mx);
    Wsum += wgt;
    o += wgt * __half2float(Op[((size_t)q * nsplit + i) * DIMD + d]);
  }
  Out[(size_t)q * DIMD + d] = o / Wsum;
}

extern "C" void kernel_launch(void* const* d_in, const int* in_sizes, int n_in,
                              void* d_out, int out_size, void* d_ws, size_t ws_size,
                              hipStream_t stream) {
  const float* X = (const float*)d_in[0];
  const float* W = (const float*)d_in[1];
  const float* bias = (const float*)d_in[2];
  char* wsb = (char*)d_ws;
  ushort* qw = (ushort*)wsb;                       // 8 MB
  ushort* kw = qw + (size_t)16384 * 256;           // 8 MB
  ushort* vtw = kw + (size_t)16384 * 256;          // 8 MB (V^T, j-permuted)
  ushort* wt = vtw + (size_t)16384 * 256;          // 384 KB (W^T bf16)
  const size_t head_bytes = (size_t)3 * 16384 * 256 * 2 + 768 * 256 * 2;
  const size_t per_split = (size_t)16384 * 256 * 2 + (size_t)16384 * 4;  // fp16 O + fp32 M
  int nsplit = 1;
  if (ws_size >= head_bytes + 4 * per_split)      nsplit = 4;
  else if (ws_size >= head_bytes + 2 * per_split) nsplit = 2;
  __half* Op = (__half*)(wsb + head_bytes);
  float* Mp = (float*)(wsb + head_bytes + (size_t)nsplit * 16384 * 256 * 2);

  wt_prep<<<dim3(24), 256, 0, stream>>>(W, wt);
  qkv_proj<<<dim3(128, 3), 256, 0, stream>>>(X, wt, bias, qw, kw, vtw);
  flash_attn<<<dim3(64 * nsplit), 512, 0, stream>>>(qw, kw, vtw, (float*)d_out,
                                                    Op, Mp, nsplit, 4096 / nsplit);
  if (nsplit > 1)
    attn_merge<<<dim3(16384), 256, 0, stream>>>(Op, Mp, (float*)d_out, nsplit);
}